// Round 1
// baseline (880.811 us; speedup 1.0000x reference)
//
#include <hip/hip_runtime.h>
#include <math.h>

#define N_NODES 100000
#define N_EDGES 1600000
#define IN_CH 128
#define OUT_CH 64
#define HC 128      // HEADS*OUT_CH
#define EDGE_DIM 32

// ---------------- K1: quantize w_lin, build v_edge ----------------
__global__ __launch_bounds__(256) void k_prep(const float* __restrict__ w_lin,
                                              const float* __restrict__ w_edge,
                                              const float* __restrict__ att_edge,
                                              float* __restrict__ qw,
                                              float* __restrict__ ve) {
    __shared__ float red[256];
    __shared__ float sscale;
    int t = threadIdx.x;
    float m = 0.f;
    for (int i = t; i < HC * IN_CH; i += 256) m = fmaxf(m, fabsf(w_lin[i]));
    red[t] = m;
    __syncthreads();
    for (int off = 128; off > 0; off >>= 1) {
        if (t < off) red[t] = fmaxf(red[t], red[t + off]);
        __syncthreads();
    }
    if (t == 0) sscale = red[0] / 127.0f + 1e-12f;
    __syncthreads();
    float scale = sscale;
    for (int i = t; i < HC * IN_CH; i += 256) {
        float q = rintf(w_lin[i] / scale);
        q = fminf(127.f, fmaxf(-128.f, q));
        qw[i] = q * scale;
    }
    // v_edge[h][k] = sum_c att_edge[h,c] * w_edge[h*64+c, k]
    if (t < 64) {
        int h = t >> 5, k = t & 31;
        float s = 0.f;
        for (int c = 0; c < OUT_CH; ++c)
            s += att_edge[h * OUT_CH + c] * w_edge[(h * OUT_CH + c) * EDGE_DIM + k];
        ve[h * EDGE_DIM + k] = s;
    }
}

// ---------------- K2: xp = x @ qw^T  (N x 128) ----------------
__global__ __launch_bounds__(256) void k_proj(const float* __restrict__ x,
                                              const float* __restrict__ qw,
                                              float* __restrict__ xp) {
    __shared__ float xs[128 * 128];  // 64KB, XOR-swizzled
    const int nb = blockIdx.x * 128;
    for (int i = threadIdx.x; i < 4096; i += 256) {
        int w = i << 2;
        int row = w >> 7;
        int col = w & 127;
        int gn = nb + row;
        float4 v = make_float4(0.f, 0.f, 0.f, 0.f);
        if (gn < N_NODES) v = *(const float4*)(x + (size_t)gn * IN_CH + col);
        int scol = col ^ (((row >> 3) & 3) << 2);
        *(float4*)(&xs[row * 128 + scol]) = v;
    }
    __syncthreads();
    const int cg = threadIdx.x & 15;
    const int ng = threadIdx.x >> 4;
    const int c0 = cg << 3;
    const int n0 = ng << 3;
    float acc[8][8];
#pragma unroll
    for (int i = 0; i < 8; i++)
#pragma unroll
        for (int j = 0; j < 8; j++) acc[i][j] = 0.f;

    const int swz = ((ng & 3) << 2);  // (n>>3)&3 == ng&3 for n in [n0, n0+8)
    for (int k = 0; k < 128; k += 4) {
        float4 xv[8], wv[8];
#pragma unroll
        for (int i = 0; i < 8; i++)
            xv[i] = *(const float4*)(&xs[(n0 + i) * 128 + (k ^ swz)]);
#pragma unroll
        for (int j = 0; j < 8; j++)
            wv[j] = *(const float4*)(qw + (c0 + j) * IN_CH + k);
#pragma unroll
        for (int i = 0; i < 8; i++)
#pragma unroll
            for (int j = 0; j < 8; j++)
                acc[i][j] += xv[i].x * wv[j].x + xv[i].y * wv[j].y +
                             xv[i].z * wv[j].z + xv[i].w * wv[j].w;
    }
#pragma unroll
    for (int i = 0; i < 8; i++) {
        int gn = nb + n0 + i;
        if (gn < N_NODES) {
            float4 o0 = make_float4(acc[i][0], acc[i][1], acc[i][2], acc[i][3]);
            float4 o1 = make_float4(acc[i][4], acc[i][5], acc[i][6], acc[i][7]);
            *(float4*)(xp + (size_t)gn * HC + c0) = o0;
            *(float4*)(xp + (size_t)gn * HC + c0 + 4) = o1;
        }
    }
}

// ---------------- K2b: per-node attention logits ----------------
__global__ __launch_bounds__(256) void k_attn_node(const float* __restrict__ xp,
                                                   const float* __restrict__ att_src,
                                                   const float* __restrict__ att_dst,
                                                   float* __restrict__ a_src,
                                                   float* __restrict__ a_dst) {
    int n = blockIdx.x * 4 + (threadIdx.x >> 6);
    int lane = threadIdx.x & 63;
    if (n >= N_NODES) return;
    float x0 = xp[(size_t)n * HC + lane];
    float x1 = xp[(size_t)n * HC + 64 + lane];
    float s0 = x0 * att_src[lane];
    float s1 = x1 * att_src[64 + lane];
    float d0 = x0 * att_dst[lane];
    float d1 = x1 * att_dst[64 + lane];
    for (int off = 32; off > 0; off >>= 1) {
        s0 += __shfl_xor(s0, off, 64);
        s1 += __shfl_xor(s1, off, 64);
        d0 += __shfl_xor(d0, off, 64);
        d1 += __shfl_xor(d1, off, 64);
    }
    if (lane == 0) {
        ((float2*)a_src)[n] = make_float2(s0, s1);
        ((float2*)a_dst)[n] = make_float2(d0, d1);
    }
}

// ---------------- K3: per-edge alpha (leaky-relu'd logits) + dst histogram ----------------
__global__ __launch_bounds__(256) void k_edge(const int* __restrict__ ei,
                                              const float* __restrict__ ea,
                                              const float* __restrict__ ve,
                                              const float* __restrict__ a_src,
                                              const float* __restrict__ a_dst,
                                              float* __restrict__ alpha,
                                              int* __restrict__ counts) {
    __shared__ float lds[256 * 33];  // padded stride 33: conflict-free
    __shared__ float vel[64];
    int t = threadIdx.x;
    int base = blockIdx.x * 256;
    if (t < 64) vel[t] = ve[t];
    for (int i = t; i < 256 * EDGE_DIM; i += 256)
        lds[(i >> 5) * 33 + (i & 31)] = ea[(size_t)base * EDGE_DIM + i];
    __syncthreads();
    int e = base + t;
    int src = ei[e];
    int dst = ei[N_EDGES + e];
    float ae0 = 0.f, ae1 = 0.f;
    const float* row = &lds[t * 33];
#pragma unroll
    for (int k = 0; k < 32; k++) {
        ae0 += row[k] * vel[k];
        ae1 += row[k] * vel[32 + k];
    }
    float2 as = ((const float2*)a_src)[src];
    float2 ad = ((const float2*)a_dst)[dst];
    float al0 = as.x + ad.x + ae0;
    float al1 = as.y + ad.y + ae1;
    al0 = al0 >= 0.f ? al0 : 0.2f * al0;
    al1 = al1 >= 0.f ? al1 : 0.2f * al1;
    ((float2*)alpha)[e] = make_float2(al0, al1);
    atomicAdd(&counts[dst], 1);
}

// ---------------- K4: CSR offsets (block sums -> scan -> offsets) ----------------
__global__ __launch_bounds__(256) void k_bsum(const int* __restrict__ counts, int* __restrict__ bsums) {
    __shared__ int s[256];
    int i = blockIdx.x * 256 + threadIdx.x;
    int v = (i < N_NODES) ? counts[i] : 0;
    s[threadIdx.x] = v;
    __syncthreads();
    for (int off = 128; off > 0; off >>= 1) {
        if (threadIdx.x < off) s[threadIdx.x] += s[threadIdx.x + off];
        __syncthreads();
    }
    if (threadIdx.x == 0) bsums[blockIdx.x] = s[0];
}

__global__ __launch_bounds__(512) void k_bscan(const int* __restrict__ bsums, int* __restrict__ boff, int nb) {
    __shared__ int s[512];
    int t = threadIdx.x;
    int v = (t < nb) ? bsums[t] : 0;
    s[t] = v;
    __syncthreads();
    for (int off = 1; off < 512; off <<= 1) {
        int add = (t >= off) ? s[t - off] : 0;
        __syncthreads();
        s[t] += add;
        __syncthreads();
    }
    if (t < nb) boff[t] = s[t] - v;  // exclusive
}

__global__ __launch_bounds__(256) void k_offsets(const int* __restrict__ counts,
                                                 const int* __restrict__ boff,
                                                 int* __restrict__ offsets) {
    __shared__ int s[256];
    int t = threadIdx.x;
    int i = blockIdx.x * 256 + t;
    int v = (i < N_NODES) ? counts[i] : 0;
    s[t] = v;
    __syncthreads();
    for (int off = 1; off < 256; off <<= 1) {
        int add = (t >= off) ? s[t - off] : 0;
        __syncthreads();
        s[t] += add;
        __syncthreads();
    }
    if (i < N_NODES) offsets[i] = boff[blockIdx.x] + s[t] - v;
    if (i == 0) offsets[N_NODES] = N_EDGES;
}

// ---------------- K5: scatter edges into CSR order ----------------
__global__ __launch_bounds__(256) void k_scatter(const int* __restrict__ ei,
                                                 const float* __restrict__ alpha,
                                                 int* __restrict__ cursors,
                                                 int* __restrict__ src_sorted,
                                                 float* __restrict__ alpha_sorted) {
    int e = blockIdx.x * 256 + threadIdx.x;
    int src = ei[e];
    int dst = ei[N_EDGES + e];
    float2 a = ((const float2*)alpha)[e];
    int pos = atomicAdd(&cursors[dst], 1);
    src_sorted[pos] = src;
    ((float2*)alpha_sorted)[pos] = a;
}

// ---------------- K6: per-node softmax + weighted aggregate ----------------
__global__ __launch_bounds__(256) void k_aggregate(const int* __restrict__ offsets,
                                                   const int* __restrict__ src_sorted,
                                                   const float* __restrict__ alpha_sorted,
                                                   const float* __restrict__ xp,
                                                   const float* __restrict__ bias,
                                                   float* __restrict__ out) {
    int n = blockIdx.x * 4 + (threadIdx.x >> 6);
    if (n >= N_NODES) return;
    int lane = threadIdx.x & 63;
    int start = offsets[n], end = offsets[n + 1];
    float m0 = -INFINITY, m1 = -INFINITY;
    for (int j = start + lane; j < end; j += 64) {
        float2 a = ((const float2*)alpha_sorted)[j];
        m0 = fmaxf(m0, a.x);
        m1 = fmaxf(m1, a.y);
    }
    for (int off = 32; off > 0; off >>= 1) {
        m0 = fmaxf(m0, __shfl_xor(m0, off, 64));
        m1 = fmaxf(m1, __shfl_xor(m1, off, 64));
    }
    float accA = 0.f, accB = 0.f, d0 = 0.f, d1 = 0.f;
    int j = start;
    int s_next = 0;
    float2 a_next = make_float2(0.f, 0.f);
    if (j < end) {
        s_next = src_sorted[j];
        a_next = ((const float2*)alpha_sorted)[j];
    }
    for (; j < end; ++j) {
        int sc = s_next;
        float2 ac = a_next;
        if (j + 1 < end) {
            s_next = src_sorted[j + 1];
            a_next = ((const float2*)alpha_sorted)[j + 1];
        }
        float ex0 = expf(ac.x - m0);
        float ex1 = expf(ac.y - m1);
        d0 += ex0;
        d1 += ex1;
        const float* r = xp + (size_t)sc * HC;
        accA += ex0 * r[lane];
        accB += ex1 * r[64 + lane];
    }
    float o = 0.5f * (accA / (d0 + 1e-16f) + accB / (d1 + 1e-16f)) + bias[lane];
    out[(size_t)n * OUT_CH + lane] = o;
}

// ---------------- K7: output fake-quant ----------------
__global__ __launch_bounds__(256) void k_absmax(const float* __restrict__ v, unsigned int* __restrict__ amax) {
    float m = 0.f;
    int stride = gridDim.x * 256;
    for (int i = blockIdx.x * 256 + threadIdx.x; i < N_NODES * OUT_CH / 4; i += stride) {
        float4 x = ((const float4*)v)[i];
        m = fmaxf(m, fmaxf(fmaxf(fabsf(x.x), fabsf(x.y)), fmaxf(fabsf(x.z), fabsf(x.w))));
    }
    for (int off = 32; off > 0; off >>= 1) m = fmaxf(m, __shfl_xor(m, off, 64));
    if ((threadIdx.x & 63) == 0) atomicMax(amax, __float_as_uint(m));
}

__global__ __launch_bounds__(256) void k_quant_out(float* __restrict__ v, const unsigned int* __restrict__ amax) {
    float scale = __uint_as_float(*amax) / 127.0f + 1e-12f;
    int i = blockIdx.x * 256 + threadIdx.x;
    float4 x = ((const float4*)v)[i];
    float qx = fminf(127.f, fmaxf(-128.f, rintf(x.x / scale)));
    float qy = fminf(127.f, fmaxf(-128.f, rintf(x.y / scale)));
    float qz = fminf(127.f, fmaxf(-128.f, rintf(x.z / scale)));
    float qw_ = fminf(127.f, fmaxf(-128.f, rintf(x.w / scale)));
    ((float4*)v)[i] = make_float4(qx * scale, qy * scale, qz * scale, qw_ * scale);
}

extern "C" void kernel_launch(void* const* d_in, const int* in_sizes, int n_in,
                              void* d_out, int out_size, void* d_ws, size_t ws_size,
                              hipStream_t stream) {
    const float* x        = (const float*)d_in[0];
    const int*   ei       = (const int*)d_in[1];
    const float* ea       = (const float*)d_in[2];
    const float* w_lin    = (const float*)d_in[3];
    const float* w_edge   = (const float*)d_in[4];
    const float* att_src  = (const float*)d_in[5];
    const float* att_dst  = (const float*)d_in[6];
    const float* att_edge = (const float*)d_in[7];
    const float* bias     = (const float*)d_in[8];
    float* out = (float*)d_out;

    char* ws = (char*)d_ws;
    size_t off = 0;
    auto alloc = [&](size_t b) {
        void* p = ws + off;
        off = (off + b + 255) & ~(size_t)255;
        return p;
    };
    float* qw           = (float*)alloc((size_t)HC * IN_CH * 4);
    float* ve           = (float*)alloc(64 * 4);
    float* xp           = (float*)alloc((size_t)N_NODES * HC * 4);
    float* a_src        = (float*)alloc((size_t)N_NODES * 2 * 4);
    float* a_dst        = (float*)alloc((size_t)N_NODES * 2 * 4);
    float* alpha        = (float*)alloc((size_t)N_EDGES * 2 * 4);
    int*   counts       = (int*)alloc((size_t)N_NODES * 4);
    int*   offsets      = (int*)alloc((size_t)(N_NODES + 1) * 4);
    int*   cursors      = (int*)alloc((size_t)N_NODES * 4);
    int*   bsums        = (int*)alloc(512 * 4);
    int*   boff         = (int*)alloc(512 * 4);
    int*   src_sorted   = (int*)alloc((size_t)N_EDGES * 4);
    float* alpha_sorted = (float*)alloc((size_t)N_EDGES * 2 * 4);
    unsigned int* amax  = (unsigned int*)alloc(256);

    hipMemsetAsync(counts, 0, (size_t)N_NODES * 4, stream);
    hipMemsetAsync(amax, 0, 4, stream);

    k_prep<<<1, 256, 0, stream>>>(w_lin, w_edge, att_edge, qw, ve);
    k_proj<<<(N_NODES + 127) / 128, 256, 0, stream>>>(x, qw, xp);
    k_attn_node<<<(N_NODES + 3) / 4, 256, 0, stream>>>(xp, att_src, att_dst, a_src, a_dst);
    k_edge<<<N_EDGES / 256, 256, 0, stream>>>(ei, ea, ve, a_src, a_dst, alpha, counts);
    int nb = (N_NODES + 255) / 256;  // 391
    k_bsum<<<nb, 256, 0, stream>>>(counts, bsums);
    k_bscan<<<1, 512, 0, stream>>>(bsums, boff, nb);
    k_offsets<<<nb, 256, 0, stream>>>(counts, boff, offsets);
    hipMemcpyAsync(cursors, offsets, (size_t)N_NODES * 4, hipMemcpyDeviceToDevice, stream);
    k_scatter<<<N_EDGES / 256, 256, 0, stream>>>(ei, alpha, cursors, src_sorted, alpha_sorted);
    k_aggregate<<<(N_NODES + 3) / 4, 256, 0, stream>>>(offsets, src_sorted, alpha_sorted, xp, bias, out);
    k_absmax<<<1024, 256, 0, stream>>>(out, amax);
    k_quant_out<<<(N_NODES * OUT_CH / 4) / 256, 256, 0, stream>>>(out, amax);
}

// Round 2
// 730.787 us; speedup vs baseline: 1.2053x; 1.2053x over previous
//
#include <hip/hip_runtime.h>
#include <math.h>

#define N_NODES 100000
#define N_EDGES 1600000
#define IN_CH 128
#define OUT_CH 64
#define HC 128      // HEADS*OUT_CH
#define EDGE_DIM 32

typedef __bf16 bf16x8 __attribute__((ext_vector_type(8)));
typedef float f32x4 __attribute__((ext_vector_type(4)));

// ---------------- K1: quantize w_lin -> integer-valued bf16 + scale, build v_edge ----------------
__global__ __launch_bounds__(256) void k_prep(const float* __restrict__ w_lin,
                                              const float* __restrict__ w_edge,
                                              const float* __restrict__ att_edge,
                                              __bf16* __restrict__ qwb,
                                              float* __restrict__ qscale,
                                              float* __restrict__ ve) {
    __shared__ float red[256];
    __shared__ float sscale;
    int t = threadIdx.x;
    float m = 0.f;
    for (int i = t; i < HC * IN_CH; i += 256) m = fmaxf(m, fabsf(w_lin[i]));
    red[t] = m;
    __syncthreads();
    for (int off = 128; off > 0; off >>= 1) {
        if (t < off) red[t] = fmaxf(red[t], red[t + off]);
        __syncthreads();
    }
    if (t == 0) { sscale = red[0] / 127.0f + 1e-12f; qscale[0] = sscale; }
    __syncthreads();
    float scale = sscale;
    for (int i = t; i < HC * IN_CH; i += 256) {
        float q = rintf(w_lin[i] / scale);
        q = fminf(127.f, fmaxf(-128.f, q));
        qwb[i] = (__bf16)q;   // integer in [-128,127]: exact in bf16
    }
    // v_edge[h][k] = sum_c att_edge[h,c] * w_edge[h*64+c, k]
    if (t < 64) {
        int h = t >> 5, k = t & 31;
        float s = 0.f;
        for (int c = 0; c < OUT_CH; ++c)
            s += att_edge[h * OUT_CH + c] * w_edge[(h * OUT_CH + c) * EDGE_DIM + k];
        ve[h * EDGE_DIM + k] = s;
    }
}

// ---------------- K2: xp = scale * (x @ q^T) via bf16 MFMA (hi/lo split for fp32 accuracy)
//                  fused: per-node attention logits a_src/a_dst ----------------
__global__ __launch_bounds__(256) void k_proj(const float* __restrict__ x,
                                              const __bf16* __restrict__ qwb,
                                              const float* __restrict__ qscale,
                                              const float* __restrict__ att_src,
                                              const float* __restrict__ att_dst,
                                              float* __restrict__ xp,
                                              float* __restrict__ a_src,
                                              float* __restrict__ a_dst) {
    const int wave = threadIdx.x >> 6;
    const int lane = threadIdx.x & 63;
    const int cl = lane & 15;     // col-in-tile / row-in-tile selector
    const int kg = lane >> 4;     // k-group 0..3 (8 consecutive k each)
    const int nb = blockIdx.x * 128 + wave * 32;  // this wave's first node

    f32x4 acc[2][8];
#pragma unroll
    for (int mt = 0; mt < 2; ++mt)
#pragma unroll
        for (int nt = 0; nt < 8; ++nt)
            acc[mt][nt] = (f32x4){0.f, 0.f, 0.f, 0.f};

    const int kb0 = kg * 8;
#pragma unroll
    for (int kc = 0; kc < 4; ++kc) {
        const int kb = kc * 32 + kb0;
        bf16x8 ah[2], al[2];
#pragma unroll
        for (int mt = 0; mt < 2; ++mt) {
            int row = nb + mt * 16 + cl;
            float v[8];
            if (row < N_NODES) {
                f32x4 v0 = *(const f32x4*)(x + (size_t)row * IN_CH + kb);
                f32x4 v1 = *(const f32x4*)(x + (size_t)row * IN_CH + kb + 4);
                v[0] = v0.x; v[1] = v0.y; v[2] = v0.z; v[3] = v0.w;
                v[4] = v1.x; v[5] = v1.y; v[6] = v1.z; v[7] = v1.w;
            } else {
#pragma unroll
                for (int i = 0; i < 8; ++i) v[i] = 0.f;
            }
#pragma unroll
            for (int i = 0; i < 8; ++i) {
                __bf16 h = (__bf16)v[i];
                ah[mt][i] = h;
                al[mt][i] = (__bf16)(v[i] - (float)h);
            }
        }
#pragma unroll
        for (int nt = 0; nt < 8; ++nt) {
            bf16x8 bw = *(const bf16x8*)(qwb + (size_t)(nt * 16 + cl) * IN_CH + kb);
            acc[0][nt] = __builtin_amdgcn_mfma_f32_16x16x32_bf16(ah[0], bw, acc[0][nt], 0, 0, 0);
            acc[0][nt] = __builtin_amdgcn_mfma_f32_16x16x32_bf16(al[0], bw, acc[0][nt], 0, 0, 0);
            acc[1][nt] = __builtin_amdgcn_mfma_f32_16x16x32_bf16(ah[1], bw, acc[1][nt], 0, 0, 0);
            acc[1][nt] = __builtin_amdgcn_mfma_f32_16x16x32_bf16(al[1], bw, acc[1][nt], 0, 0, 0);
        }
    }

    const float scale = qscale[0];
#pragma unroll
    for (int mt = 0; mt < 2; ++mt)
#pragma unroll
        for (int nt = 0; nt < 8; ++nt)
#pragma unroll
            for (int r = 0; r < 4; ++r) acc[mt][nt][r] *= scale;

    // ---- store xp: D layout col=lane&15, row=(lane>>4)*4+reg ----
#pragma unroll
    for (int mt = 0; mt < 2; ++mt) {
#pragma unroll
        for (int r = 0; r < 4; ++r) {
            int n = nb + mt * 16 + kg * 4 + r;
            if (n < N_NODES) {
#pragma unroll
                for (int nt = 0; nt < 8; ++nt)
                    xp[(size_t)n * HC + nt * 16 + cl] = acc[mt][nt][r];
            }
        }
    }

    // ---- fused per-node attention logits ----
#pragma unroll
    for (int mt = 0; mt < 2; ++mt) {
        float s0[4] = {0.f, 0.f, 0.f, 0.f}, s1[4] = {0.f, 0.f, 0.f, 0.f};
        float d0[4] = {0.f, 0.f, 0.f, 0.f}, d1[4] = {0.f, 0.f, 0.f, 0.f};
#pragma unroll
        for (int nt = 0; nt < 8; ++nt) {
            int col = nt * 16 + cl;
            float as_ = att_src[col];
            float ad_ = att_dst[col];
#pragma unroll
            for (int r = 0; r < 4; ++r) {
                float v = acc[mt][nt][r];
                if (nt < 4) { s0[r] += v * as_; d0[r] += v * ad_; }
                else        { s1[r] += v * as_; d1[r] += v * ad_; }
            }
        }
#pragma unroll
        for (int off = 1; off < 16; off <<= 1) {
#pragma unroll
            for (int r = 0; r < 4; ++r) {
                s0[r] += __shfl_xor(s0[r], off, 64);
                s1[r] += __shfl_xor(s1[r], off, 64);
                d0[r] += __shfl_xor(d0[r], off, 64);
                d1[r] += __shfl_xor(d1[r], off, 64);
            }
        }
        if (cl == 0) {
#pragma unroll
            for (int r = 0; r < 4; ++r) {
                int n = nb + mt * 16 + kg * 4 + r;
                if (n < N_NODES) {
                    ((float2*)a_src)[n] = make_float2(s0[r], s1[r]);
                    ((float2*)a_dst)[n] = make_float2(d0[r], d1[r]);
                }
            }
        }
    }
}

// ---------------- K3: dst histogram ----------------
__global__ __launch_bounds__(256) void k_count(const int* __restrict__ ei, int* __restrict__ counts) {
    int e = blockIdx.x * 256 + threadIdx.x;
    atomicAdd(&counts[ei[N_EDGES + e]], 1);
}

// ---------------- K4: CSR offsets (block sums -> scan -> offsets) ----------------
__global__ __launch_bounds__(256) void k_bsum(const int* __restrict__ counts, int* __restrict__ bsums) {
    __shared__ int s[256];
    int i = blockIdx.x * 256 + threadIdx.x;
    int v = (i < N_NODES) ? counts[i] : 0;
    s[threadIdx.x] = v;
    __syncthreads();
    for (int off = 128; off > 0; off >>= 1) {
        if (threadIdx.x < off) s[threadIdx.x] += s[threadIdx.x + off];
        __syncthreads();
    }
    if (threadIdx.x == 0) bsums[blockIdx.x] = s[0];
}

__global__ __launch_bounds__(512) void k_bscan(const int* __restrict__ bsums, int* __restrict__ boff, int nb) {
    __shared__ int s[512];
    int t = threadIdx.x;
    int v = (t < nb) ? bsums[t] : 0;
    s[t] = v;
    __syncthreads();
    for (int off = 1; off < 512; off <<= 1) {
        int add = (t >= off) ? s[t - off] : 0;
        __syncthreads();
        s[t] += add;
        __syncthreads();
    }
    if (t < nb) boff[t] = s[t] - v;  // exclusive
}

__global__ __launch_bounds__(256) void k_offsets(const int* __restrict__ counts,
                                                 const int* __restrict__ boff,
                                                 int* __restrict__ offsets) {
    __shared__ int s[256];
    int t = threadIdx.x;
    int i = blockIdx.x * 256 + t;
    int v = (i < N_NODES) ? counts[i] : 0;
    s[t] = v;
    __syncthreads();
    for (int off = 1; off < 256; off <<= 1) {
        int add = (t >= off) ? s[t - off] : 0;
        __syncthreads();
        s[t] += add;
        __syncthreads();
    }
    if (i < N_NODES) offsets[i] = boff[blockIdx.x] + s[t] - v;
    if (i == 0) offsets[N_NODES] = N_EDGES;
}

// ---------------- K5: per-edge alpha + scatter into CSR order ----------------
__global__ __launch_bounds__(256) void k_scatter_alpha(const int* __restrict__ ei,
                                                       const float* __restrict__ ea,
                                                       const float* __restrict__ ve,
                                                       const float* __restrict__ a_src,
                                                       const float* __restrict__ a_dst,
                                                       int* __restrict__ cursors,
                                                       int* __restrict__ src_sorted,
                                                       float* __restrict__ alpha_sorted) {
    __shared__ float lds[256 * 33];  // padded stride 33: conflict-free
    __shared__ float vel[64];
    int t = threadIdx.x;
    int base = blockIdx.x * 256;
    if (t < 64) vel[t] = ve[t];
    for (int i = t; i < 256 * EDGE_DIM; i += 256)
        lds[(i >> 5) * 33 + (i & 31)] = ea[(size_t)base * EDGE_DIM + i];
    __syncthreads();
    int e = base + t;
    int src = ei[e];
    int dst = ei[N_EDGES + e];
    float ae0 = 0.f, ae1 = 0.f;
    const float* row = &lds[t * 33];
#pragma unroll
    for (int k = 0; k < 32; k++) {
        ae0 += row[k] * vel[k];
        ae1 += row[k] * vel[32 + k];
    }
    float2 as = ((const float2*)a_src)[src];
    float2 ad = ((const float2*)a_dst)[dst];
    float al0 = as.x + ad.x + ae0;
    float al1 = as.y + ad.y + ae1;
    al0 = al0 >= 0.f ? al0 : 0.2f * al0;
    al1 = al1 >= 0.f ? al1 : 0.2f * al1;
    int pos = atomicAdd(&cursors[dst], 1);
    src_sorted[pos] = src;
    ((float2*)alpha_sorted)[pos] = make_float2(al0, al1);
}

// ---------------- K6: per-node softmax + weighted aggregate ----------------
__global__ __launch_bounds__(256) void k_aggregate(const int* __restrict__ offsets,
                                                   const int* __restrict__ src_sorted,
                                                   const float* __restrict__ alpha_sorted,
                                                   const float* __restrict__ xp,
                                                   const float* __restrict__ bias,
                                                   float* __restrict__ out) {
    int n = blockIdx.x * 4 + (threadIdx.x >> 6);
    if (n >= N_NODES) return;
    int lane = threadIdx.x & 63;
    int start = offsets[n], end = offsets[n + 1];
    float m0 = -INFINITY, m1 = -INFINITY;
    for (int j = start + lane; j < end; j += 64) {
        float2 a = ((const float2*)alpha_sorted)[j];
        m0 = fmaxf(m0, a.x);
        m1 = fmaxf(m1, a.y);
    }
    for (int off = 32; off > 0; off >>= 1) {
        m0 = fmaxf(m0, __shfl_xor(m0, off, 64));
        m1 = fmaxf(m1, __shfl_xor(m1, off, 64));
    }
    float accA = 0.f, accB = 0.f, d0 = 0.f, d1 = 0.f;
    int j = start;
    int s_next = 0;
    float2 a_next = make_float2(0.f, 0.f);
    if (j < end) {
        s_next = src_sorted[j];
        a_next = ((const float2*)alpha_sorted)[j];
    }
    for (; j < end; ++j) {
        int sc = s_next;
        float2 ac = a_next;
        if (j + 1 < end) {
            s_next = src_sorted[j + 1];
            a_next = ((const float2*)alpha_sorted)[j + 1];
        }
        float ex0 = __expf(ac.x - m0);
        float ex1 = __expf(ac.y - m1);
        d0 += ex0;
        d1 += ex1;
        const float* r = xp + (size_t)sc * HC;
        accA += ex0 * r[lane];
        accB += ex1 * r[64 + lane];
    }
    float o = 0.5f * (accA / (d0 + 1e-16f) + accB / (d1 + 1e-16f)) + bias[lane];
    out[(size_t)n * OUT_CH + lane] = o;
}

// ---------------- K7: output fake-quant ----------------
__global__ __launch_bounds__(256) void k_absmax(const float* __restrict__ v, unsigned int* __restrict__ amax) {
    float m = 0.f;
    int stride = gridDim.x * 256;
    for (int i = blockIdx.x * 256 + threadIdx.x; i < N_NODES * OUT_CH / 4; i += stride) {
        float4 x = ((const float4*)v)[i];
        m = fmaxf(m, fmaxf(fmaxf(fabsf(x.x), fabsf(x.y)), fmaxf(fabsf(x.z), fabsf(x.w))));
    }
    for (int off = 32; off > 0; off >>= 1) m = fmaxf(m, __shfl_xor(m, off, 64));
    if ((threadIdx.x & 63) == 0) atomicMax(amax, __float_as_uint(m));
}

__global__ __launch_bounds__(256) void k_quant_out(float* __restrict__ v, const unsigned int* __restrict__ amax) {
    float scale = __uint_as_float(*amax) / 127.0f + 1e-12f;
    int i = blockIdx.x * 256 + threadIdx.x;
    float4 x = ((const float4*)v)[i];
    float qx = fminf(127.f, fmaxf(-128.f, rintf(x.x / scale)));
    float qy = fminf(127.f, fmaxf(-128.f, rintf(x.y / scale)));
    float qz = fminf(127.f, fmaxf(-128.f, rintf(x.z / scale)));
    float qw_ = fminf(127.f, fmaxf(-128.f, rintf(x.w / scale)));
    ((float4*)v)[i] = make_float4(qx * scale, qy * scale, qz * scale, qw_ * scale);
}

extern "C" void kernel_launch(void* const* d_in, const int* in_sizes, int n_in,
                              void* d_out, int out_size, void* d_ws, size_t ws_size,
                              hipStream_t stream) {
    const float* x        = (const float*)d_in[0];
    const int*   ei       = (const int*)d_in[1];
    const float* ea       = (const float*)d_in[2];
    const float* w_lin    = (const float*)d_in[3];
    const float* w_edge   = (const float*)d_in[4];
    const float* att_src  = (const float*)d_in[5];
    const float* att_dst  = (const float*)d_in[6];
    const float* att_edge = (const float*)d_in[7];
    const float* bias     = (const float*)d_in[8];
    float* out = (float*)d_out;

    char* ws = (char*)d_ws;
    size_t off = 0;
    auto alloc = [&](size_t b) {
        void* p = ws + off;
        off = (off + b + 255) & ~(size_t)255;
        return p;
    };
    __bf16* qwb         = (__bf16*)alloc((size_t)HC * IN_CH * 2);
    float* qscale       = (float*)alloc(256);
    float* ve           = (float*)alloc(64 * 4);
    float* xp           = (float*)alloc((size_t)N_NODES * HC * 4);
    float* a_src        = (float*)alloc((size_t)N_NODES * 2 * 4);
    float* a_dst        = (float*)alloc((size_t)N_NODES * 2 * 4);
    int*   counts       = (int*)alloc((size_t)N_NODES * 4);
    int*   offsets      = (int*)alloc((size_t)(N_NODES + 1) * 4);
    int*   cursors      = (int*)alloc((size_t)N_NODES * 4);
    int*   bsums        = (int*)alloc(512 * 4);
    int*   boff         = (int*)alloc(512 * 4);
    int*   src_sorted   = (int*)alloc((size_t)N_EDGES * 4);
    float* alpha_sorted = (float*)alloc((size_t)N_EDGES * 2 * 4);
    unsigned int* amax  = (unsigned int*)alloc(256);

    hipMemsetAsync(counts, 0, (size_t)N_NODES * 4, stream);
    hipMemsetAsync(amax, 0, 4, stream);

    k_prep<<<1, 256, 0, stream>>>(w_lin, w_edge, att_edge, qwb, qscale, ve);
    k_proj<<<(N_NODES + 127) / 128, 256, 0, stream>>>(x, qwb, qscale, att_src, att_dst, xp, a_src, a_dst);
    k_count<<<N_EDGES / 256, 256, 0, stream>>>(ei, counts);
    int nb = (N_NODES + 255) / 256;  // 391
    k_bsum<<<nb, 256, 0, stream>>>(counts, bsums);
    k_bscan<<<1, 512, 0, stream>>>(bsums, boff, nb);
    k_offsets<<<nb, 256, 0, stream>>>(counts, boff, offsets);
    hipMemcpyAsync(cursors, offsets, (size_t)N_NODES * 4, hipMemcpyDeviceToDevice, stream);
    k_scatter_alpha<<<N_EDGES / 256, 256, 0, stream>>>(ei, ea, ve, a_src, a_dst, cursors, src_sorted, alpha_sorted);
    k_aggregate<<<(N_NODES + 3) / 4, 256, 0, stream>>>(offsets, src_sorted, alpha_sorted, xp, bias, out);
    k_absmax<<<1024, 256, 0, stream>>>(out, amax);
    k_quant_out<<<(N_NODES * OUT_CH / 4) / 256, 256, 0, stream>>>(out, amax);
}